// Round 3
// baseline (995.276 us; speedup 1.0000x reference)
//
#include <hip/hip_runtime.h>

// Problem dims (fixed by setup_inputs)
#define HH 384
#define WW 512
#define NB 4
#define HWP (HH * WW)       // 196608
#define NPIX (NB * HWP)     // 786432
#define SH 96
#define SW 128
#define SHW (SH * SW)

// Strict-IEEE f32 bilinear 4x upsample of (10*flow), replicating a numpy
// mirror of jax.image.resize: scale applied to source first (one rounding),
// flat 4-term weighted sum left-to-right, every product/add rounded
// separately (NO fma contraction). Weights are exact binary fractions.
static __device__ __forceinline__ float upsample_flow_f32(const float* __restrict__ f, int y, int x) {
    float sx = __fadd_rn(__fmul_rn((float)x, 0.25f), -0.375f);  // exact
    float sy = __fadd_rn(__fmul_rn((float)y, 0.25f), -0.375f);  // exact
    float fx0 = floorf(sx), fy0 = floorf(sy);
    float wx = __fsub_rn(sx, fx0);   // exact: {0.625,0.875,0.125,0.375}
    float wy = __fsub_rn(sy, fy0);
    int ix = (int)fx0, iy = (int)fy0;
    int x0 = max(ix, 0), x1 = min(ix + 1, SW - 1);
    int y0 = max(iy, 0), y1 = min(iy + 1, SH - 1);
    float v00 = __fmul_rn(10.0f, f[y0 * SW + x0]);
    float v01 = __fmul_rn(10.0f, f[y0 * SW + x1]);
    float v10 = __fmul_rn(10.0f, f[y1 * SW + x0]);
    float v11 = __fmul_rn(10.0f, f[y1 * SW + x1]);
    float omx = __fsub_rn(1.0f, wx);  // exact
    float omy = __fsub_rn(1.0f, wy);  // exact
    float w00 = __fmul_rn(omx, omy);  // exact (few-bit significands)
    float w10 = __fmul_rn(wx, omy);
    float w01 = __fmul_rn(omx, wy);
    float w11 = __fmul_rn(wx, wy);
    float s = __fmul_rn(w00, v00);
    s = __fadd_rn(s, __fmul_rn(w10, v01));
    s = __fadd_rn(s, __fmul_rn(w01, v10));
    s = __fadd_rn(s, __fmul_rn(w11, v11));
    return s;
}

// Forward scatter: acc layout = [accx | accy | cnt], each NPIX floats
__global__ void scatter_k(const float* __restrict__ flow, float* __restrict__ acc) {
    int idx = blockIdx.x * blockDim.x + threadIdx.x;
    if (idx >= NPIX) return;
    int x = idx % WW;
    int y = (idx / WW) % HH;
    int b = idx / HWP;
    const float* fp = flow + b * 2 * SHW;
    float fx = upsample_flow_f32(fp, y, x);
    float fy = upsample_flow_f32(fp + SHW, y, x);
    float x2 = __fadd_rn((float)x, fx);
    float y2 = __fadd_rn((float)y, fy);
    if (x2 >= 0.0f && x2 <= (float)(WW - 1) && y2 >= 0.0f && y2 <= (float)(HH - 1)) {
        int xf = (int)floorf(x2);
        int yf = (int)floorf(y2);
        float nfx = -fx;
        float nfy = -fy;
        float* accx = acc;
        float* accy = acc + NPIX;
        float* cnt  = acc + 2 * NPIX;
        #pragma unroll
        for (int dy = 0; dy < 2; dy++) {
            int yi = min(max(yf + dy, 0), HH - 1);
            #pragma unroll
            for (int dx = 0; dx < 2; dx++) {
                int xi = min(max(xf + dx, 0), WW - 1);
                int o = b * HWP + yi * WW + xi;
                atomicAdd(accx + o, nfx);
                atomicAdd(accy + o, nfy);
                atomicAdd(cnt + o, 1.0f);
            }
        }
    }
}

// In-place avg = acc / max(cnt,1), both sides in one launch
__global__ void avg_k(float* __restrict__ acc0, float* __restrict__ acc1) {
    int idx = blockIdx.x * blockDim.x + threadIdx.x;
    if (idx >= NPIX) return;
    {
        float c = fmaxf(acc0[2 * NPIX + idx], 1.0f);
        acc0[idx] = acc0[idx] / c;
        acc0[NPIX + idx] = acc0[NPIX + idx] / c;
    }
    {
        float c = fmaxf(acc1[2 * NPIX + idx], 1.0f);
        acc1[idx] = acc1[idx] / c;
        acc1[NPIX + idx] = acc1[NPIX + idx] / c;
    }
}

// Hole fill: Ft layout = [Ftx | Fty]
__global__ void fill_k(const float* __restrict__ acc, float* __restrict__ Ft) {
    int idx = blockIdx.x * blockDim.x + threadIdx.x;
    if (idx >= NPIX) return;
    int x = idx % WW;
    int y = (idx / WW) % HH;
    const float* accx = acc;
    const float* accy = acc + NPIX;
    const float* cnt  = acc + 2 * NPIX;
    float c = cnt[idx];
    float ox, oy;
    if (c > 0.0f) {
        ox = accx[idx];
        oy = accy[idx];
    } else {
        float nx = 0.0f, ny = 0.0f, den = 0.0f;
        if (y > 0)      { int o = idx - WW; if (cnt[o] > 0.0f) { nx += accx[o]; ny += accy[o]; den += 1.0f; } }
        if (y < HH - 1) { int o = idx + WW; if (cnt[o] > 0.0f) { nx += accx[o]; ny += accy[o]; den += 1.0f; } }
        if (x > 0)      { int o = idx - 1;  if (cnt[o] > 0.0f) { nx += accx[o]; ny += accy[o]; den += 1.0f; } }
        if (x < WW - 1) { int o = idx + 1;  if (cnt[o] > 0.0f) { nx += accx[o]; ny += accy[o]; den += 1.0f; } }
        float inv = 1.0f / fmaxf(den, 1.0f);
        ox = nx * inv;
        oy = ny * inv;
    }
    Ft[idx] = ox;
    Ft[NPIX + idx] = oy;
}

// Filter interpolation for both sides, fused with final 0.5*(a+b)
__global__ void interp_k(const float* __restrict__ img0, const float* __restrict__ img2,
                         const float* __restrict__ filt0, const float* __restrict__ filt1,
                         const float* __restrict__ Ft0, const float* __restrict__ Ft2,
                         float* __restrict__ out) {
    int idx = blockIdx.x * blockDim.x + threadIdx.x;
    if (idx >= NPIX) return;
    int x = idx % WW;
    int y = (idx / WW) % HH;
    int b = idx / HWP;
    float res[3] = {0.0f, 0.0f, 0.0f};
    #pragma unroll
    for (int s = 0; s < 2; s++) {
        const float* img  = s ? img2  : img0;
        const float* filt = s ? filt1 : filt0;
        const float* Ft   = s ? Ft2   : Ft0;
        float fx = Ft[idx];
        float fy = Ft[NPIX + idx];
        float x2 = fminf(fmaxf((float)x + fx, 0.0f), (float)(WW - 1));
        float y2 = fminf(fmaxf((float)y + fy, 0.0f), (float)(HH - 1));
        float xff = floorf(x2), yff = floorf(y2);
        int xf = (int)xff, yf = (int)yff;
        float a  = x2 - xff;
        float bb = y2 - yff;
        float w00 = (1.0f - a) * (1.0f - bb);
        float w10 = a * (1.0f - bb);
        float w01 = (1.0f - a) * bb;
        float w11 = a * bb;
        // load 4x4 filter taps for this pixel
        float F[4][4];
        #pragma unroll
        for (int k = 0; k < 16; k++) {
            F[k >> 2][k & 3] = filt[((b * 16 + k) * HH + y) * WW + x];
        }
        // fold bilinear weights into a 5x5 effective coefficient map
        float Cf[5][5];
        #pragma unroll
        for (int r = 0; r < 5; r++) {
            #pragma unroll
            for (int sc = 0; sc < 5; sc++) {
                float v = 0.0f;
                if (r < 4 && sc < 4)   v += w00 * F[r][sc];
                if (r < 4 && sc >= 1)  v += w10 * F[r][sc - 1];
                if (r >= 1 && sc < 4)  v += w01 * F[r - 1][sc];
                if (r >= 1 && sc >= 1) v += w11 * F[r - 1][sc - 1];
                Cf[r][sc] = v;
            }
        }
        int rows[5], cols[5];
        #pragma unroll
        for (int r = 0; r < 5; r++) rows[r] = min(max(yf - 1 + r, 0), HH - 1);
        #pragma unroll
        for (int sc = 0; sc < 5; sc++) cols[sc] = min(max(xf - 1 + sc, 0), WW - 1);
        #pragma unroll
        for (int c = 0; c < 3; c++) {
            const float* ip = img + (b * 3 + c) * HWP;
            float accv = 0.0f;
            #pragma unroll
            for (int r = 0; r < 5; r++) {
                const float* rp = ip + rows[r] * WW;
                #pragma unroll
                for (int sc = 0; sc < 5; sc++) {
                    accv += Cf[r][sc] * rp[cols[sc]];
                }
            }
            res[c] += accv;
        }
    }
    #pragma unroll
    for (int c = 0; c < 3; c++) {
        out[((b * 3 + c) * HH + y) * WW + x] = 0.5f * res[c];
    }
}

extern "C" void kernel_launch(void* const* d_in, const int* in_sizes, int n_in,
                              void* d_out, int out_size, void* d_ws, size_t ws_size,
                              hipStream_t stream) {
    const float* input0 = (const float*)d_in[0];
    const float* input2 = (const float*)d_in[1];
    const float* flow01 = (const float*)d_in[2];
    const float* flow10 = (const float*)d_in[3];
    const float* filt0  = (const float*)d_in[4];
    const float* filt1  = (const float*)d_in[5];
    float* out = (float*)d_out;

    float* ws = (float*)d_ws;
    float* acc0 = ws;                    // 3*NPIX: accx, accy, cnt (side 0)
    float* acc1 = ws + 3 * NPIX;         // 3*NPIX (side 1)
    float* Ft0  = ws + 6 * NPIX;         // 2*NPIX: Ftx, Fty
    float* Ft2  = ws + 8 * NPIX;         // 2*NPIX

    // zero both accumulator regions (contiguous)
    hipMemsetAsync(acc0, 0, (size_t)6 * NPIX * sizeof(float), stream);

    const int BS = 256;
    const int NBLK = (NPIX + BS - 1) / BS;

    scatter_k<<<NBLK, BS, 0, stream>>>(flow01, acc0);
    scatter_k<<<NBLK, BS, 0, stream>>>(flow10, acc1);
    avg_k<<<NBLK, BS, 0, stream>>>(acc0, acc1);
    fill_k<<<NBLK, BS, 0, stream>>>(acc0, Ft0);
    fill_k<<<NBLK, BS, 0, stream>>>(acc1, Ft2);
    interp_k<<<NBLK, BS, 0, stream>>>(input0, input2, filt0, filt1, Ft0, Ft2, out);
}